// Round 2
// baseline (1023.126 us; speedup 1.0000x reference)
//
#include <hip/hip_runtime.h>
#include <climits>

#define NN 50000
#define EE 1600000
#define DIN 128
#define DOUT 64
#define BN_EPS 1e-5f

#define NPB 64                      // nodes per bucket (dst>>6)
#define NB  782                     // ceil(NN/NPB)
#define CAPB 3072                   // slots per bucket (Poisson(2048)+22 sigma)
#define KA_WGS 256
#define KA_CHUNK (EE / KA_WGS)      // 6250 exactly

// ---------------- K0: init scratch ----------------
__global__ void k0_init(int* gcur, float* colsum, float* colsq) {
    int i = blockIdx.x * blockDim.x + threadIdx.x;
    if (i < NB) gcur[i] = 0;
    if (i < DOUT) { colsum[i] = 0.f; colsq[i] = 0.f; }
}

// ---------------- K1: h = x @ W^T  (+ per-node attention scalars) ----------------
__global__ void k1_gemm(const float* __restrict__ x, const float* __restrict__ W,
                        const float* __restrict__ ne,
                        const float* __restrict__ atti, const float* __restrict__ attj,
                        const float* __restrict__ atemi, const float* __restrict__ atemj,
                        float* __restrict__ h, float* __restrict__ a_i, float* __restrict__ a_j) {
    const int l = threadIdx.x & 63;
    const int wv = threadIdx.x >> 6;
    const int gw = blockIdx.x * (blockDim.x >> 6) + wv;
    const int nw = gridDim.x * (blockDim.x >> 6);

    float4 w4[32];
    const float4* Wv = (const float4*)(W + l * DIN);
#pragma unroll
    for (int j = 0; j < 32; ++j) w4[j] = Wv[j];

    const float ai_l = atti[l], aj_l = attj[l], emi_l = atemi[l], emj_l = atemj[l];

    for (int n = gw; n < NN; n += nw) {
        const float4* xv = (const float4*)(x + n * DIN);
        float acc = 0.f;
#pragma unroll
        for (int j = 0; j < 32; ++j) {
            float4 xx = xv[j];
            acc += w4[j].x * xx.x + w4[j].y * xx.y + w4[j].z * xx.z + w4[j].w * xx.w;
        }
        float nev = ne[n * DOUT + l];
        float v1 = acc * ai_l + nev * emi_l;
        float v2 = acc * aj_l + nev * emj_l;
#pragma unroll
        for (int d = 32; d >= 1; d >>= 1) {
            v1 += __shfl_xor(v1, d);
            v2 += __shfl_xor(v2, d);
        }
        h[n * DOUT + l] = acc;
        if (l == 0) { a_i[n] = v1; a_j[n] = v2; }
    }
}

// ---------------- KA: bin edges by dst bucket (packed 4B records) ----------------
__global__ void __launch_bounds__(KA_WGS) kA_bin(const int* __restrict__ ei,
                                                 int* __restrict__ gcur,
                                                 unsigned int* __restrict__ binned) {
    __shared__ int hist[NB];
    __shared__ int base_l[NB];
    __shared__ unsigned int recs[KA_CHUNK];  // 25 KB
    const int t = threadIdx.x;
    for (int i = t; i < NB; i += KA_WGS) hist[i] = 0;
    __syncthreads();
    const int e0 = blockIdx.x * KA_CHUNK;
    for (int e = e0 + t; e < e0 + KA_CHUNK; e += KA_WGS) {
        int src = ei[e];
        int dst = ei[EE + e];
        atomicAdd(&hist[dst >> 6], 1);
        recs[e - e0] = (unsigned)src | ((unsigned)dst << 16);  // both < 65536
    }
    __syncthreads();
    for (int b = t; b < NB; b += KA_WGS) {
        int c = hist[b];
        base_l[b] = c > 0 ? atomicAdd(&gcur[b], c) : 0;
        hist[b] = 0;  // reuse as running local offset
    }
    __syncthreads();
    for (int e = e0 + t; e < e0 + KA_CHUNK; e += KA_WGS) {
        unsigned r = recs[e - e0];
        int dst = r >> 16;
        int b = dst >> 6;
        int pos = base_l[b] + atomicAdd(&hist[b], 1);
        binned[b * CAPB + pos] = (r & 0xffffu) | ((unsigned)(dst & 63) << 16);
    }
}

// ---------------- KB: per-bucket softmax-weighted aggregation in LDS ----------------
__global__ void __launch_bounds__(256) kB_agg(const unsigned int* __restrict__ binned,
                                              const int* __restrict__ gcur,
                                              const float* __restrict__ h,
                                              const float* __restrict__ a_i,
                                              const float* __restrict__ a_j,
                                              const float* __restrict__ bias,
                                              float* __restrict__ out_pre,
                                              float* __restrict__ colsum,
                                              float* __restrict__ colsq) {
    __shared__ float agg[NPB * DOUT];   // 16 KB
    __shared__ float s_l[NPB];
    __shared__ float ai_l[NPB];
    const int b = blockIdx.x;
    const int node0 = b * NPB;
    const int nlocal = min(NPB, NN - node0);
    const int t = threadIdx.x;
    const int l = t & 63, wv = t >> 6;
    const float bias_l = bias[l];

    for (int i = t; i < NPB * DOUT; i += 256) agg[i] = 0.f;
    if (t < NPB) {
        s_l[t] = 0.f;
        ai_l[t] = (t < nlocal) ? a_i[node0 + t] : 0.f;
    }
    __syncthreads();

    const int cnt = gcur[b];
    const unsigned int* bin = binned + b * CAPB;

    for (int base = wv * 64; base < cnt; base += 256) {
        const int kk = min(64, cnt - base);
        unsigned r = (l < kk) ? bin[base + l] : 0u;
        int src = r & 0xffffu;
        int dl = (r >> 16) & 63;
        float ev = 0.f;
        if (l < kk) {
            float lg = ai_l[dl] + a_j[src];
            lg = lg > 0.f ? lg : 0.2f * lg;
            ev = __expf(lg);
            atomicAdd(&s_l[dl], ev);
        }
        if (kk == 64) {
#pragma unroll
            for (int k = 0; k < 64; ++k) {
                int srcK = __shfl(src, k);
                int dlK = __shfl(dl, k);
                float evK = __shfl(ev, k);
                float hv = h[srcK * 64 + l];
                atomicAdd(&agg[dlK * 64 + l], evK * hv);
            }
        } else {
            for (int k = 0; k < kk; ++k) {
                int srcK = __shfl(src, k);
                int dlK = __shfl(dl, k);
                float evK = __shfl(ev, k);
                float hv = h[srcK * 64 + l];
                atomicAdd(&agg[dlK * 64 + l], evK * hv);
            }
        }
    }
    __syncthreads();

    // epilogue: normalize, bias, write out_pre, BN partial sums
    float bsum = 0.f, bsq = 0.f;
    for (int j = wv; j < nlocal; j += 4) {
        float v = agg[j * 64 + l] / (s_l[j] + 1e-16f) + bias_l;
        out_pre[(node0 + j) * 64 + l] = v;
        bsum += v;
        bsq += v * v;
    }
    __syncthreads();
    agg[wv * 64 + l] = bsum;
    agg[256 + wv * 64 + l] = bsq;
    __syncthreads();
    if (wv == 0) {
        float ts = agg[l] + agg[64 + l] + agg[128 + l] + agg[192 + l];
        float tq = agg[256 + l] + agg[320 + l] + agg[384 + l] + agg[448 + l];
        atomicAdd(&colsum[l], ts);
        atomicAdd(&colsq[l], tq);
    }
}

// ---------------- K6: BN coefficients ----------------
__global__ void k6_coef(const float* __restrict__ colsum, const float* __restrict__ colsq,
                        const float* __restrict__ gamma, const float* __restrict__ beta,
                        float* __restrict__ scale, float* __restrict__ shift) {
    int c = threadIdx.x;
    if (c < DOUT) {
        float mean = colsum[c] * (1.f / NN);
        float var = colsq[c] * (1.f / NN) - mean * mean;
        float inv = rsqrtf(var + BN_EPS);
        float sc = gamma[c] * inv;
        scale[c] = sc;
        shift[c] = beta[c] - mean * sc;
    }
}

// ---------------- K7: y = relu(out*scale + shift), vectorized ----------------
__global__ void k7_apply(const float4* __restrict__ out_pre,
                         const float4* __restrict__ scale, const float4* __restrict__ shift,
                         float4* __restrict__ y) {
    const int n4 = NN * DOUT / 4;
    int tid = blockIdx.x * blockDim.x + threadIdx.x;
    int stride = gridDim.x * blockDim.x;
    for (int i = tid; i < n4; i += stride) {
        float4 o = out_pre[i];
        int c = i & 15;
        float4 sc = scale[c], sh = shift[c];
        float4 r;
        r.x = fmaxf(o.x * sc.x + sh.x, 0.f);
        r.y = fmaxf(o.y * sc.y + sh.y, 0.f);
        r.z = fmaxf(o.z * sc.z + sh.z, 0.f);
        r.w = fmaxf(o.w * sc.w + sh.w, 0.f);
        y[i] = r;
    }
}

extern "C" void kernel_launch(void* const* d_in, const int* in_sizes, int n_in,
                              void* d_out, int out_size, void* d_ws, size_t ws_size,
                              hipStream_t stream) {
    const float* x      = (const float*)d_in[0];
    const int*   ei     = (const int*)d_in[1];
    const float* ne     = (const float*)d_in[2];
    const float* W      = (const float*)d_in[3];
    const float* att_i  = (const float*)d_in[4];
    const float* att_j  = (const float*)d_in[5];
    const float* atemi  = (const float*)d_in[6];
    const float* atemj  = (const float*)d_in[7];
    const float* bias   = (const float*)d_in[8];
    const float* gamma  = (const float*)d_in[9];
    const float* beta   = (const float*)d_in[10];
    float* out = (float*)d_out;

    char* w = (char*)d_ws;
    size_t off = 0;
    auto alloc = [&](size_t bytes) -> void* {
        void* p = w + off;
        off = (off + bytes + 255) & ~(size_t)255;
        return p;
    };
    float*        h       = (float*)alloc((size_t)NN * DOUT * 4);
    float*        out_pre = (float*)alloc((size_t)NN * DOUT * 4);
    unsigned int* binned  = (unsigned int*)alloc((size_t)NB * CAPB * 4);
    float*        a_i     = (float*)alloc((size_t)NN * 4);
    float*        a_j     = (float*)alloc((size_t)NN * 4);
    int*          gcur    = (int*)alloc((size_t)NB * 4);
    float*        colsum  = (float*)alloc(DOUT * 4);
    float*        colsq   = (float*)alloc(DOUT * 4);
    float*        scale   = (float*)alloc(DOUT * 4);
    float*        shift   = (float*)alloc(DOUT * 4);

    k0_init<<<(NB + 255) / 256, 256, 0, stream>>>(gcur, colsum, colsq);
    k1_gemm<<<1024, 256, 0, stream>>>(x, W, ne, att_i, att_j, atemi, atemj, h, a_i, a_j);
    kA_bin<<<KA_WGS, KA_WGS, 0, stream>>>(ei, gcur, binned);
    kB_agg<<<NB, 256, 0, stream>>>(binned, gcur, h, a_i, a_j, bias, out_pre, colsum, colsq);
    k6_coef<<<1, 64, 0, stream>>>(colsum, colsq, gamma, beta, scale, shift);
    k7_apply<<<1024, 256, 0, stream>>>((const float4*)out_pre, (const float4*)scale,
                                       (const float4*)shift, (float4*)out);
}

// Round 4
// 889.907 us; speedup vs baseline: 1.1497x; 1.1497x over previous
//
#include <hip/hip_runtime.h>
#include <climits>

#define NN 50000
#define EE 1600000
#define DIN 128
#define DOUT 64
#define BN_EPS 1e-5f

#define NPB 32                      // nodes per bucket (dst>>5)
#define NB  1563                    // ceil(NN/NPB)
#define CAPB 1536                   // slots per bucket (Poisson(1024) + 16 sigma)
#define KA_WGS 512                  // number of binning workgroups
#define KA_CHUNK (EE / KA_WGS)      // 3125 exactly

// ---------------- K0: init scratch ----------------
__global__ void k0_init(int* gcur, float* colsum, float* colsq) {
    int i = blockIdx.x * blockDim.x + threadIdx.x;
    if (i < NB) gcur[i] = 0;
    if (i < DOUT) { colsum[i] = 0.f; colsq[i] = 0.f; }
}

// ---------------- K1: h = x @ W^T  (+ per-node attention scalars) ----------------
__global__ void k1_gemm(const float* __restrict__ x, const float* __restrict__ W,
                        const float* __restrict__ ne,
                        const float* __restrict__ atti, const float* __restrict__ attj,
                        const float* __restrict__ atemi, const float* __restrict__ atemj,
                        float* __restrict__ h, float* __restrict__ a_i, float* __restrict__ a_j) {
    const int l = threadIdx.x & 63;
    const int wv = threadIdx.x >> 6;
    const int gw = blockIdx.x * (blockDim.x >> 6) + wv;
    const int nw = gridDim.x * (blockDim.x >> 6);

    float4 w4[32];
    const float4* Wv = (const float4*)(W + l * DIN);
#pragma unroll
    for (int j = 0; j < 32; ++j) w4[j] = Wv[j];

    const float ai_l = atti[l], aj_l = attj[l], emi_l = atemi[l], emj_l = atemj[l];

    for (int n = gw; n < NN; n += nw) {
        const float4* xv = (const float4*)(x + n * DIN);
        float acc = 0.f;
#pragma unroll
        for (int j = 0; j < 32; ++j) {
            float4 xx = xv[j];
            acc += w4[j].x * xx.x + w4[j].y * xx.y + w4[j].z * xx.z + w4[j].w * xx.w;
        }
        float nev = ne[n * DOUT + l];
        float v1 = acc * ai_l + nev * emi_l;
        float v2 = acc * aj_l + nev * emj_l;
#pragma unroll
        for (int d = 32; d >= 1; d >>= 1) {
            v1 += __shfl_xor(v1, d);
            v2 += __shfl_xor(v2, d);
        }
        h[n * DOUT + l] = acc;
        if (l == 0) { a_i[n] = v1; a_j[n] = v2; }
    }
}

// ---------------- KA: bin edges by dst bucket (packed 4B records) ----------------
__global__ void __launch_bounds__(256) kA_bin(const int* __restrict__ ei,
                                              int* __restrict__ gcur,
                                              unsigned int* __restrict__ binned) {
    __shared__ int hist[NB];
    __shared__ int base_l[NB];
    __shared__ unsigned int recs[KA_CHUNK];  // 12.5 KB
    const int t = threadIdx.x;
    for (int i = t; i < NB; i += 256) hist[i] = 0;
    __syncthreads();
    const int e0 = blockIdx.x * KA_CHUNK;
    for (int e = e0 + t; e < e0 + KA_CHUNK; e += 256) {
        int src = ei[e];
        int dst = ei[EE + e];
        atomicAdd(&hist[dst >> 5], 1);
        recs[e - e0] = (unsigned)src | ((unsigned)dst << 16);  // both < 65536
    }
    __syncthreads();
    for (int b = t; b < NB; b += 256) {
        int c = hist[b];
        base_l[b] = c > 0 ? atomicAdd(&gcur[b], c) : 0;
        hist[b] = 0;  // reuse as running local offset
    }
    __syncthreads();
    for (int e = e0 + t; e < e0 + KA_CHUNK; e += 256) {
        unsigned r = recs[e - e0];
        int dst = r >> 16;
        int b = dst >> 5;
        int pos = base_l[b] + atomicAdd(&hist[b], 1);
        binned[b * CAPB + pos] = (r & 0xffffu) | ((unsigned)(dst & 31) << 16);
    }
}

// ---------------- KB: per-bucket softmax-weighted aggregation in LDS ----------------
__global__ void __launch_bounds__(256) kB_agg(const unsigned int* __restrict__ binned,
                                              const int* __restrict__ gcur,
                                              const float* __restrict__ h,
                                              const float* __restrict__ a_i,
                                              const float* __restrict__ a_j,
                                              const float* __restrict__ bias,
                                              float* __restrict__ out_pre,
                                              float* __restrict__ colsum,
                                              float* __restrict__ colsq) {
    __shared__ float agg[NPB * DOUT];   // 8 KB
    __shared__ float s_l[NPB];
    __shared__ float ai_l[NPB];
    const int b = blockIdx.x;
    const int node0 = b * NPB;
    const int nlocal = min(NPB, NN - node0);
    const int t = threadIdx.x;
    const int l = t & 63, wv = t >> 6;
    const float bias_l = bias[l];

    for (int i = t; i < NPB * DOUT; i += 256) agg[i] = 0.f;
    if (t < NPB) {
        s_l[t] = 0.f;
        ai_l[t] = (t < nlocal) ? a_i[node0 + t] : 0.f;
    }
    __syncthreads();

    const int cnt = gcur[b];
    const unsigned int* bin = binned + b * CAPB;

    for (int base = wv * 64; base < cnt; base += 256) {
        const int kk = min(64, cnt - base);
        unsigned r = (l < kk) ? bin[base + l] : 0u;
        int src = r & 0xffffu;
        int dl = (r >> 16) & 31;
        float ev = 0.f;
        if (l < kk) {
            float lg = ai_l[dl] + a_j[src];
            lg = lg > 0.f ? lg : 0.2f * lg;
            ev = __expf(lg);
            atomicAdd(&s_l[dl], ev);
        }
        int evi = __float_as_int(ev);
        if (kk == 64) {
#pragma unroll
            for (int kb = 0; kb < 64; kb += 16) {
                float hv[16];
                float evb[16];
                int   db[16];
#pragma unroll
                for (int u = 0; u < 16; ++u) {
                    int k = kb + u;
                    int sK = __builtin_amdgcn_readlane(src, k);
                    db[u] = __builtin_amdgcn_readlane(dl, k);
                    evb[u] = __int_as_float(__builtin_amdgcn_readlane(evi, k));
                    hv[u] = h[(sK << 6) + l];
                }
#pragma unroll
                for (int u = 0; u < 16; ++u)
                    atomicAdd(&agg[(db[u] << 6) + l], evb[u] * hv[u]);
            }
        } else {
            for (int k = 0; k < kk; ++k) {
                int sK = __builtin_amdgcn_readlane(src, k);
                int dK = __builtin_amdgcn_readlane(dl, k);
                float eK = __int_as_float(__builtin_amdgcn_readlane(evi, k));
                float hvv = h[(sK << 6) + l];
                atomicAdd(&agg[(dK << 6) + l], eK * hvv);
            }
        }
    }
    __syncthreads();

    // epilogue: normalize, bias, write out_pre, BN partial sums
    float bsum = 0.f, bsq = 0.f;
    for (int j = wv; j < nlocal; j += 4) {
        float v = agg[j * 64 + l] / (s_l[j] + 1e-16f) + bias_l;
        out_pre[(node0 + j) * 64 + l] = v;
        bsum += v;
        bsq += v * v;
    }
    __syncthreads();
    agg[wv * 64 + l] = bsum;
    agg[256 + wv * 64 + l] = bsq;
    __syncthreads();
    if (wv == 0) {
        float ts = agg[l] + agg[64 + l] + agg[128 + l] + agg[192 + l];
        float tq = agg[256 + l] + agg[320 + l] + agg[384 + l] + agg[448 + l];
        atomicAdd(&colsum[l], ts);
        atomicAdd(&colsq[l], tq);
    }
}

// ---------------- K6: BN coefficients ----------------
__global__ void k6_coef(const float* __restrict__ colsum, const float* __restrict__ colsq,
                        const float* __restrict__ gamma, const float* __restrict__ beta,
                        float* __restrict__ scale, float* __restrict__ shift) {
    int c = threadIdx.x;
    if (c < DOUT) {
        float mean = colsum[c] * (1.f / NN);
        float var = colsq[c] * (1.f / NN) - mean * mean;
        float inv = rsqrtf(var + BN_EPS);
        float sc = gamma[c] * inv;
        scale[c] = sc;
        shift[c] = beta[c] - mean * sc;
    }
}

// ---------------- K7: y = relu(out*scale + shift), vectorized ----------------
__global__ void k7_apply(const float4* __restrict__ out_pre,
                         const float4* __restrict__ scale, const float4* __restrict__ shift,
                         float4* __restrict__ y) {
    const int n4 = NN * DOUT / 4;
    int tid = blockIdx.x * blockDim.x + threadIdx.x;
    int stride = gridDim.x * blockDim.x;
    for (int i = tid; i < n4; i += stride) {
        float4 o = out_pre[i];
        int c = i & 15;
        float4 sc = scale[c], sh = shift[c];
        float4 r;
        r.x = fmaxf(o.x * sc.x + sh.x, 0.f);
        r.y = fmaxf(o.y * sc.y + sh.y, 0.f);
        r.z = fmaxf(o.z * sc.z + sh.z, 0.f);
        r.w = fmaxf(o.w * sc.w + sh.w, 0.f);
        y[i] = r;
    }
}

extern "C" void kernel_launch(void* const* d_in, const int* in_sizes, int n_in,
                              void* d_out, int out_size, void* d_ws, size_t ws_size,
                              hipStream_t stream) {
    const float* x      = (const float*)d_in[0];
    const int*   ei     = (const int*)d_in[1];
    const float* ne     = (const float*)d_in[2];
    const float* W      = (const float*)d_in[3];
    const float* att_i  = (const float*)d_in[4];
    const float* att_j  = (const float*)d_in[5];
    const float* atemi  = (const float*)d_in[6];
    const float* atemj  = (const float*)d_in[7];
    const float* bias   = (const float*)d_in[8];
    const float* gamma  = (const float*)d_in[9];
    const float* beta   = (const float*)d_in[10];
    float* out = (float*)d_out;

    char* w = (char*)d_ws;
    size_t off = 0;
    auto alloc = [&](size_t bytes) -> void* {
        void* p = w + off;
        off = (off + bytes + 255) & ~(size_t)255;
        return p;
    };
    float*        h       = (float*)alloc((size_t)NN * DOUT * 4);
    float*        out_pre = (float*)alloc((size_t)NN * DOUT * 4);
    unsigned int* binned  = (unsigned int*)alloc((size_t)NB * CAPB * 4);
    float*        a_i     = (float*)alloc((size_t)NN * 4);
    float*        a_j     = (float*)alloc((size_t)NN * 4);
    int*          gcur    = (int*)alloc((size_t)NB * 4);
    float*        colsum  = (float*)alloc(DOUT * 4);
    float*        colsq   = (float*)alloc(DOUT * 4);
    float*        scale   = (float*)alloc(DOUT * 4);
    float*        shift   = (float*)alloc(DOUT * 4);

    k0_init<<<(NB + 255) / 256, 256, 0, stream>>>(gcur, colsum, colsq);
    k1_gemm<<<1024, 256, 0, stream>>>(x, W, ne, att_i, att_j, atemi, atemj, h, a_i, a_j);
    kA_bin<<<KA_WGS, 256, 0, stream>>>(ei, gcur, binned);
    kB_agg<<<NB, 256, 0, stream>>>(binned, gcur, h, a_i, a_j, bias, out_pre, colsum, colsq);
    k6_coef<<<1, 64, 0, stream>>>(colsum, colsq, gamma, beta, scale, shift);
    k7_apply<<<1024, 256, 0, stream>>>((const float4*)out_pre, (const float4*)scale,
                                       (const float4*)shift, (float4*)out);
}

// Round 5
// 878.329 us; speedup vs baseline: 1.1649x; 1.0132x over previous
//
#include <hip/hip_runtime.h>
#include <climits>

#define NN 50000
#define EE 1600000
#define DIN 128
#define DOUT 64
#define BN_EPS 1e-5f

#define NPB 32                      // nodes per fine bucket (dst>>5)
#define NB  1563                    // ceil(NN/NPB)
#define CAPB 1536                   // slots per fine bucket (Poisson(1024) + 16 sigma)
#define NCB 49                      // coarse buckets (dst>>10), 49999>>10 = 48
#define CAPC 35200                  // slots per coarse bucket (Poisson(32653) + 14 sigma)
#define KA1_WGS 512
#define KA1_CHUNK (EE / KA1_WGS)    // 3125
#define KA2_SPLIT 16                // WGs per coarse bucket

// ---------------- K0: init scratch ----------------
__global__ void k0_init(int* gcur, int* gcurC, float* colsum, float* colsq) {
    int i = blockIdx.x * blockDim.x + threadIdx.x;
    if (i < NB + 8) gcur[i] = 0;
    if (i < NCB) gcurC[i] = 0;
    if (i < DOUT) { colsum[i] = 0.f; colsq[i] = 0.f; }
}

// ---------------- K1: h = x @ W^T  (+ per-node attention scalars) ----------------
__global__ void k1_gemm(const float* __restrict__ x, const float* __restrict__ W,
                        const float* __restrict__ ne,
                        const float* __restrict__ atti, const float* __restrict__ attj,
                        const float* __restrict__ atemi, const float* __restrict__ atemj,
                        float* __restrict__ h, float* __restrict__ a_i, float* __restrict__ a_j) {
    const int l = threadIdx.x & 63;
    const int wv = threadIdx.x >> 6;
    const int gw = blockIdx.x * (blockDim.x >> 6) + wv;
    const int nw = gridDim.x * (blockDim.x >> 6);

    float4 w4[32];
    const float4* Wv = (const float4*)(W + l * DIN);
#pragma unroll
    for (int j = 0; j < 32; ++j) w4[j] = Wv[j];

    const float ai_l = atti[l], aj_l = attj[l], emi_l = atemi[l], emj_l = atemj[l];

    for (int n = gw; n < NN; n += nw) {
        const float4* xv = (const float4*)(x + n * DIN);
        float acc = 0.f;
#pragma unroll
        for (int j = 0; j < 32; ++j) {
            float4 xx = xv[j];
            acc += w4[j].x * xx.x + w4[j].y * xx.y + w4[j].z * xx.z + w4[j].w * xx.w;
        }
        float nev = ne[n * DOUT + l];
        float v1 = acc * ai_l + nev * emi_l;
        float v2 = acc * aj_l + nev * emj_l;
#pragma unroll
        for (int d = 32; d >= 1; d >>= 1) {
            v1 += __shfl_xor(v1, d);
            v2 += __shfl_xor(v2, d);
        }
        h[n * DOUT + l] = acc;
        if (l == 0) { a_i[n] = v1; a_j[n] = v2; }
    }
}

// ---------------- KA1: bin edges into 49 coarse buckets ----------------
// Per-WG reservation runs ~64 edges (256 B) -> 64B lines are WG-exclusive, no ping-pong.
__global__ void __launch_bounds__(256) kA1_coarse(const int* __restrict__ ei,
                                                  int* __restrict__ gcurC,
                                                  unsigned int* __restrict__ coarse) {
    __shared__ int hist[NCB];
    __shared__ int base_l[NCB];
    __shared__ unsigned int recs[KA1_CHUNK];  // 12.5 KB
    const int t = threadIdx.x;
    if (t < NCB) hist[t] = 0;
    __syncthreads();
    const int e0 = blockIdx.x * KA1_CHUNK;
    for (int e = e0 + t; e < e0 + KA1_CHUNK; e += 256) {
        int src = ei[e];
        int dst = ei[EE + e];
        atomicAdd(&hist[dst >> 10], 1);
        recs[e - e0] = (unsigned)src | ((unsigned)dst << 16);  // both < 65536
    }
    __syncthreads();
    if (t < NCB) {
        int c = hist[t];
        base_l[t] = c > 0 ? atomicAdd(&gcurC[t], c) : 0;
        hist[t] = 0;
    }
    __syncthreads();
    for (int e = e0 + t; e < e0 + KA1_CHUNK; e += 256) {
        unsigned r = recs[e - e0];
        int cb = (r >> 16) >> 10;
        int pos = base_l[cb] + atomicAdd(&hist[cb], 1);
        coarse[cb * CAPC + pos] = r;
    }
}

// ---------------- KA2: refine each coarse bucket into 32-node fine bins ----------------
__global__ void __launch_bounds__(256) kA2_fine(const unsigned int* __restrict__ coarse,
                                                const int* __restrict__ gcurC,
                                                int* __restrict__ gcur,
                                                unsigned int* __restrict__ binned) {
    __shared__ int hist[32];
    __shared__ int base_l[32];
    __shared__ unsigned int recs[CAPC / KA2_SPLIT + 64];  // ~9 KB
    const int c = blockIdx.x >> 4;
    const int q = blockIdx.x & 15;
    const int len = gcurC[c];
    const int start = (len * q) / KA2_SPLIT;
    const int end = (len * (q + 1)) / KA2_SPLIT;
    const int t = threadIdx.x;
    if (t < 32) hist[t] = 0;
    __syncthreads();
    const unsigned int* cb = coarse + c * CAPC;
    for (int i = start + t; i < end; i += 256) {
        unsigned r = cb[i];
        recs[i - start] = r;
        atomicAdd(&hist[(r >> 21) & 31], 1);   // fine-in-coarse = (dst>>5)&31
    }
    __syncthreads();
    if (t < 32) {
        int n = hist[t];
        base_l[t] = n > 0 ? atomicAdd(&gcur[c * 32 + t], n) : 0;
        hist[t] = 0;
    }
    __syncthreads();
    for (int i = start + t; i < end; i += 256) {
        unsigned r = recs[i - start];
        int fb = (r >> 21) & 31;
        int pos = base_l[fb] + atomicAdd(&hist[fb], 1);
        // record: src | (dst&31)<<16
        binned[(c * 32 + fb) * CAPB + pos] = (r & 0xffffu) | (((r >> 16) & 31u) << 16);
    }
}

// ---------------- KB: per-bucket softmax-weighted aggregation in LDS ----------------
__global__ void __launch_bounds__(256) kB_agg(const unsigned int* __restrict__ binned,
                                              const int* __restrict__ gcur,
                                              const float* __restrict__ h,
                                              const float* __restrict__ a_i,
                                              const float* __restrict__ a_j,
                                              const float* __restrict__ bias,
                                              float* __restrict__ out_pre,
                                              float* __restrict__ colsum,
                                              float* __restrict__ colsq) {
    __shared__ float agg[NPB * DOUT];   // 8 KB
    __shared__ float s_l[NPB];
    __shared__ float ai_l[NPB];
    const int b = blockIdx.x;
    const int node0 = b * NPB;
    const int nlocal = min(NPB, NN - node0);
    const int t = threadIdx.x;
    const int l = t & 63, wv = t >> 6;
    const float bias_l = bias[l];

    for (int i = t; i < NPB * DOUT; i += 256) agg[i] = 0.f;
    if (t < NPB) {
        s_l[t] = 0.f;
        ai_l[t] = (t < nlocal) ? a_i[node0 + t] : 0.f;
    }
    __syncthreads();

    const int cnt = gcur[b];
    const unsigned int* bin = binned + b * CAPB;

    for (int base = wv * 64; base < cnt; base += 256) {
        const int kk = min(64, cnt - base);
        unsigned r = (l < kk) ? bin[base + l] : 0u;
        int src = r & 0xffffu;
        int dl = (r >> 16) & 31;
        float ev = 0.f;
        if (l < kk) {
            float lg = ai_l[dl] + a_j[src];
            lg = lg > 0.f ? lg : 0.2f * lg;
            ev = __expf(lg);
            atomicAdd(&s_l[dl], ev);
        }
        int evi = __float_as_int(ev);
        if (kk == 64) {
            float hv[64];
#pragma unroll
            for (int u = 0; u < 64; ++u) {
                int sK = __builtin_amdgcn_readlane(src, u);
                hv[u] = h[(sK << 6) + l];
            }
            // hard fence: loads above may NOT sink below -> 64 loads in flight
            __builtin_amdgcn_sched_barrier(0);
#pragma unroll
            for (int u = 0; u < 64; ++u) {
                int dK = __builtin_amdgcn_readlane(dl, u);
                float eK = __int_as_float(__builtin_amdgcn_readlane(evi, u));
                atomicAdd(&agg[(dK << 6) + l], eK * hv[u]);
            }
        } else {
            for (int k = 0; k < kk; ++k) {
                int sK = __builtin_amdgcn_readlane(src, k);
                int dK = __builtin_amdgcn_readlane(dl, k);
                float eK = __int_as_float(__builtin_amdgcn_readlane(evi, k));
                float hvv = h[(sK << 6) + l];
                atomicAdd(&agg[(dK << 6) + l], eK * hvv);
            }
        }
    }
    __syncthreads();

    // epilogue: normalize, bias, write out_pre, BN partial sums
    float bsum = 0.f, bsq = 0.f;
    for (int j = wv; j < nlocal; j += 4) {
        float v = agg[j * 64 + l] / (s_l[j] + 1e-16f) + bias_l;
        out_pre[(node0 + j) * 64 + l] = v;
        bsum += v;
        bsq += v * v;
    }
    __syncthreads();
    agg[wv * 64 + l] = bsum;
    agg[256 + wv * 64 + l] = bsq;
    __syncthreads();
    if (wv == 0) {
        float ts = agg[l] + agg[64 + l] + agg[128 + l] + agg[192 + l];
        float tq = agg[256 + l] + agg[320 + l] + agg[384 + l] + agg[448 + l];
        atomicAdd(&colsum[l], ts);
        atomicAdd(&colsq[l], tq);
    }
}

// ---------------- K6: BN coefficients ----------------
__global__ void k6_coef(const float* __restrict__ colsum, const float* __restrict__ colsq,
                        const float* __restrict__ gamma, const float* __restrict__ beta,
                        float* __restrict__ scale, float* __restrict__ shift) {
    int c = threadIdx.x;
    if (c < DOUT) {
        float mean = colsum[c] * (1.f / NN);
        float var = colsq[c] * (1.f / NN) - mean * mean;
        float inv = rsqrtf(var + BN_EPS);
        float sc = gamma[c] * inv;
        scale[c] = sc;
        shift[c] = beta[c] - mean * sc;
    }
}

// ---------------- K7: y = relu(out*scale + shift), vectorized ----------------
__global__ void k7_apply(const float4* __restrict__ out_pre,
                         const float4* __restrict__ scale, const float4* __restrict__ shift,
                         float4* __restrict__ y) {
    const int n4 = NN * DOUT / 4;
    int tid = blockIdx.x * blockDim.x + threadIdx.x;
    int stride = gridDim.x * blockDim.x;
    for (int i = tid; i < n4; i += stride) {
        float4 o = out_pre[i];
        int c = i & 15;
        float4 sc = scale[c], sh = shift[c];
        float4 r;
        r.x = fmaxf(o.x * sc.x + sh.x, 0.f);
        r.y = fmaxf(o.y * sc.y + sh.y, 0.f);
        r.z = fmaxf(o.z * sc.z + sh.z, 0.f);
        r.w = fmaxf(o.w * sc.w + sh.w, 0.f);
        y[i] = r;
    }
}

extern "C" void kernel_launch(void* const* d_in, const int* in_sizes, int n_in,
                              void* d_out, int out_size, void* d_ws, size_t ws_size,
                              hipStream_t stream) {
    const float* x      = (const float*)d_in[0];
    const int*   ei     = (const int*)d_in[1];
    const float* ne     = (const float*)d_in[2];
    const float* W      = (const float*)d_in[3];
    const float* att_i  = (const float*)d_in[4];
    const float* att_j  = (const float*)d_in[5];
    const float* atemi  = (const float*)d_in[6];
    const float* atemj  = (const float*)d_in[7];
    const float* bias   = (const float*)d_in[8];
    const float* gamma  = (const float*)d_in[9];
    const float* beta   = (const float*)d_in[10];
    float* out = (float*)d_out;

    char* w = (char*)d_ws;
    size_t off = 0;
    auto alloc = [&](size_t bytes) -> void* {
        void* p = w + off;
        off = (off + bytes + 255) & ~(size_t)255;
        return p;
    };
    float*        h       = (float*)alloc((size_t)NN * DOUT * 4);
    float*        out_pre = (float*)alloc((size_t)NN * DOUT * 4);
    unsigned int* binned  = (unsigned int*)alloc((size_t)NB * CAPB * 4);
    float*        a_i     = (float*)alloc((size_t)NN * 4);
    float*        a_j     = (float*)alloc((size_t)NN * 4);
    int*          gcur    = (int*)alloc((size_t)(NB + 8) * 4);
    int*          gcurC   = (int*)alloc((size_t)NCB * 4);
    float*        colsum  = (float*)alloc(DOUT * 4);
    float*        colsq   = (float*)alloc(DOUT * 4);
    float*        scale   = (float*)alloc(DOUT * 4);
    float*        shift   = (float*)alloc(DOUT * 4);
    // coarse buffer (6.9 MB) aliases out_pre (12.8 MB): dead before kB writes out_pre
    unsigned int* coarse  = (unsigned int*)out_pre;

    k0_init<<<(NB + 255 + 8) / 256, 256, 0, stream>>>(gcur, gcurC, colsum, colsq);
    k1_gemm<<<1024, 256, 0, stream>>>(x, W, ne, att_i, att_j, atemi, atemj, h, a_i, a_j);
    kA1_coarse<<<KA1_WGS, 256, 0, stream>>>(ei, gcurC, coarse);
    kA2_fine<<<NCB * KA2_SPLIT, 256, 0, stream>>>(coarse, gcurC, gcur, binned);
    kB_agg<<<NB, 256, 0, stream>>>(binned, gcur, h, a_i, a_j, bias, out_pre, colsum, colsq);
    k6_coef<<<1, 64, 0, stream>>>(colsum, colsq, gamma, beta, scale, shift);
    k7_apply<<<1024, 256, 0, stream>>>((const float4*)out_pre, (const float4*)scale,
                                       (const float4*)shift, (float4*)out);
}